// Round 1
// baseline (2003.199 us; speedup 1.0000x reference)
//
#include <hip/hip_runtime.h>

typedef unsigned short u16;
typedef __bf16 bf16x8 __attribute__((ext_vector_type(8)));
typedef float f32x4 __attribute__((ext_vector_type(4)));

#define L_    2048
#define D_    3072
#define NH_   24
#define HD_   128
#define MLP_  12288
#define HCOLS 21504   // 3*D + MLP
#define SCOLS 15360   // D + MLP

// ---------- helpers ----------
__device__ __forceinline__ float bf2f(u16 u) { return __uint_as_float(((unsigned)u) << 16); }
__device__ __forceinline__ u16 f2bf(float f) {
    unsigned b = __float_as_uint(f);
    b += 0x7FFF + ((b >> 16) & 1);   // RNE
    return (u16)(b >> 16);
}
__device__ __forceinline__ void gld_lds16(const u16* g, u16* l) {
    __builtin_amdgcn_global_load_lds((const __attribute__((address_space(1))) void*)g,
                                     (__attribute__((address_space(3))) void*)l, 16, 0, 0);
}

// ---------- generic batched GEMM: C = alpha * A(MxK) @ Bt(NxK)^T + bias ----------
// A, Bt bf16 row-major (row stride K). C fp32 or bf16, row stride ldC.
template <int BM, int BN>
__global__ __launch_bounds__(256) void gemm_bt(
    const u16* __restrict__ A, const u16* __restrict__ Bt,
    const float* __restrict__ bias, void* __restrict__ Cv,
    int M, int N, int K, int ldC,
    long long sA, long long sB, long long sC,
    float alpha, int outBf16)
{
    constexpr int BK = 32;
    __shared__ __align__(16) u16 As[BM * BK];
    __shared__ __align__(16) u16 Bs[BN * BK];
    const int t = threadIdx.x, w = t >> 6, lane = t & 63;
    const int quad = lane >> 4, r16 = lane & 15;
    const int m0 = blockIdx.y * BM, n0 = blockIdx.x * BN;
    const u16* Ab = A + (size_t)blockIdx.z * sA;
    const u16* Bb = Bt + (size_t)blockIdx.z * sB;
    constexpr int WM = BM / 2, WN = BN / 2, TI = WM / 16, TJ = WN / 16;
    const int wm = (w >> 1) * WM, wn = (w & 1) * WN;

    f32x4 acc[TI][TJ];
#pragma unroll
    for (int i = 0; i < TI; ++i)
#pragma unroll
        for (int j = 0; j < TJ; ++j) acc[i][j] = (f32x4){0.f, 0.f, 0.f, 0.f};

    constexpr int AR = (BM * BK * 2) / 4096;  // 1024B per wave per round
    constexpr int BR = (BN * BK * 2) / 4096;

    for (int k0 = 0; k0 < K; k0 += BK) {
#pragma unroll
        for (int r = 0; r < AR; ++r) {
            int o = r * 4096 + w * 1024 + lane * 16;  // byte offset in As
            int row = o >> 6, cb = o & 63;            // 64B per LDS row (32 bf16)
            gld_lds16(Ab + (size_t)(m0 + row) * K + k0 + (cb >> 1), As + (o >> 1));
        }
#pragma unroll
        for (int r = 0; r < BR; ++r) {
            int o = r * 4096 + w * 1024 + lane * 16;
            int row = o >> 6, cb = o & 63;
            gld_lds16(Bb + (size_t)(n0 + row) * K + k0 + (cb >> 1), Bs + (o >> 1));
        }
        __syncthreads();  // drains vmcnt (global_load_lds) too
        bf16x8 af[TI], bfr[TJ];
#pragma unroll
        for (int i = 0; i < TI; ++i)
            af[i] = *(const bf16x8*)&As[(wm + i * 16 + r16) * BK + quad * 8];
#pragma unroll
        for (int j = 0; j < TJ; ++j)
            bfr[j] = *(const bf16x8*)&Bs[(wn + j * 16 + r16) * BK + quad * 8];
#pragma unroll
        for (int i = 0; i < TI; ++i)
#pragma unroll
            for (int j = 0; j < TJ; ++j)
                acc[i][j] = __builtin_amdgcn_mfma_f32_16x16x32_bf16(af[i], bfr[j], acc[i][j], 0, 0, 0);
        __syncthreads();
    }

    // epilogue: C/D layout col = lane&15, row = quad*4 + reg  [verified m89/m91]
    if (outBf16) {
        u16* Cb = (u16*)Cv + (size_t)blockIdx.z * sC;
#pragma unroll
        for (int i = 0; i < TI; ++i)
#pragma unroll
            for (int rr = 0; rr < 4; ++rr) {
                int m = m0 + wm + i * 16 + quad * 4 + rr;
                u16* crow = Cb + (size_t)m * ldC;
#pragma unroll
                for (int j = 0; j < TJ; ++j) {
                    int n = n0 + wn + j * 16 + r16;
                    float v = acc[i][j][rr] * alpha;
                    if (bias) v += bias[n];
                    crow[n] = f2bf(v);
                }
            }
    } else {
        float* Cb = (float*)Cv + (size_t)blockIdx.z * sC;
#pragma unroll
        for (int i = 0; i < TI; ++i)
#pragma unroll
            for (int rr = 0; rr < 4; ++rr) {
                int m = m0 + wm + i * 16 + quad * 4 + rr;
                float* crow = Cb + (size_t)m * ldC;
#pragma unroll
                for (int j = 0; j < TJ; ++j) {
                    int n = n0 + wn + j * 16 + r16;
                    float v = acc[i][j][rr] * alpha;
                    if (bias) v += bias[n];
                    crow[n] = v;
                }
            }
    }
}

// ---------- transpose fp32 (R,C) -> bf16 (C,R) ----------
__global__ __launch_bounds__(256) void transpose_to_bf16(
    const float* __restrict__ in, u16* __restrict__ out, int R, int C)
{
    __shared__ float tile[32][33];
    int c0 = blockIdx.x * 32, r0 = blockIdx.y * 32;
    int tx = threadIdx.x & 31, ty = threadIdx.x >> 5;  // ty 0..7
#pragma unroll
    for (int i = 0; i < 32; i += 8)
        tile[ty + i][tx] = in[(size_t)(r0 + ty + i) * C + c0 + tx];
    __syncthreads();
#pragma unroll
    for (int i = 0; i < 32; i += 8)
        out[(size_t)(c0 + ty + i) * R + r0 + tx] = f2bf(tile[tx][ty + i]);
}

// ---------- mod: init + silu precompute ----------
__global__ void mod_init(const float* __restrict__ mod_b, const float* __restrict__ vec,
                         float* __restrict__ MOD, float* __restrict__ SVEC)
{
    int i = blockIdx.x * 256 + threadIdx.x;
    if (i < 3 * D_) MOD[i] = mod_b[i];
    if (i < D_) { float v = vec[i]; SVEC[i] = v / (1.f + __expf(-v)); }
}

// ---------- mod GEMV partial (atomic) ----------
__global__ __launch_bounds__(256) void mod_gemv(
    const float* __restrict__ SVEC, const float* __restrict__ mod_w, float* __restrict__ MOD)
{
    int n = blockIdx.x * 256 + threadIdx.x;
    int k0 = blockIdx.y * 128;
    float acc = 0.f;
#pragma unroll 8
    for (int kk = 0; kk < 128; ++kk)
        acc += SVEC[k0 + kk] * mod_w[(size_t)(k0 + kk) * (3 * D_) + n];
    atomicAdd(&MOD[n], acc);
}

// ---------- layernorm + modulation -> x_mod (bf16) ----------
__global__ __launch_bounds__(256) void ln_mod_k(
    const float* __restrict__ x, const float* __restrict__ MOD, u16* __restrict__ XMOD)
{
    int l = blockIdx.x, t = threadIdx.x;
    const float4* xr = (const float4*)(x + (size_t)l * D_);
    float4 v[3];
    float s = 0.f, ss = 0.f;
#pragma unroll
    for (int c = 0; c < 3; ++c) {
        v[c] = xr[c * 256 + t];
        s += v[c].x + v[c].y + v[c].z + v[c].w;
        ss += v[c].x * v[c].x + v[c].y * v[c].y + v[c].z * v[c].z + v[c].w * v[c].w;
    }
    __shared__ float rs[4], rss[4];
    float a = s, b = ss;
    for (int off = 32; off; off >>= 1) { a += __shfl_down(a, off); b += __shfl_down(b, off); }
    if ((t & 63) == 0) { rs[t >> 6] = a; rss[t >> 6] = b; }
    __syncthreads();
    float S = rs[0] + rs[1] + rs[2] + rs[3];
    float SS = rss[0] + rss[1] + rss[2] + rss[3];
    float mu = S * (1.f / D_);
    float var = SS * (1.f / D_) - mu * mu;
    float rstd = rsqrtf(var + 1e-6f);
    u16* orow = XMOD + (size_t)l * D_;
#pragma unroll
    for (int c = 0; c < 3; ++c) {
        int d0 = (c * 256 + t) * 4;
        float vals[4] = {v[c].x, v[c].y, v[c].z, v[c].w};
#pragma unroll
        for (int q = 0; q < 4; ++q) {
            int d = d0 + q;
            float o = MOD[d] + (1.f + MOD[D_ + d]) * ((vals[q] - mu) * rstd);
            orow[d] = f2bf(o);
        }
    }
}

// ---------- q/k: RMS norm + scale + rope -> (NH, L, HD) bf16 ----------
__global__ __launch_bounds__(128) void qkv_rope(
    const u16* __restrict__ h, const float* __restrict__ pe,
    const float* __restrict__ qs, const float* __restrict__ ks,
    u16* __restrict__ Q, u16* __restrict__ Kb)
{
    int l = blockIdx.x, nh = blockIdx.y, tt = blockIdx.z;  // tt: 0=q 1=k
    int d = threadIdx.x;                                   // 128 threads
    float xv = bf2f(h[(size_t)l * HCOLS + tt * D_ + nh * HD_ + d]);
    __shared__ float red[2];
    __shared__ float ybuf[HD_];
    float sq = xv * xv;
    for (int off = 32; off; off >>= 1) sq += __shfl_down(sq, off);
    if ((d & 63) == 0) red[d >> 6] = sq;
    __syncthreads();
    float tot = red[0] + red[1];
    float rms = rsqrtf(tot * (1.f / HD_) + 1e-6f);
    const float* scale = (tt == 0) ? qs : ks;
    float y = xv * rms * scale[d];
    ybuf[d] = y;
    __syncthreads();
    int p = d >> 1, j = d & 1;
    float e = ybuf[2 * p], o = ybuf[2 * p + 1];
    const float* pb = pe + ((size_t)l * (HD_ / 2) + p) * 4 + j * 2;
    float out = pb[0] * e + pb[1] * o;
    u16* dst = (tt == 0) ? Q : Kb;
    dst[((size_t)nh * L_ + l) * HD_ + d] = f2bf(out);
}

// ---------- v transpose -> (NH, HD, L) bf16 ----------
__global__ __launch_bounds__(256) void v_trans(const u16* __restrict__ h, u16* __restrict__ VT)
{
    int lb = blockIdx.x, nh = blockIdx.y;
    __shared__ u16 tile[HD_][65];
    int t = threadIdx.x;
#pragma unroll
    for (int it = 0; it < 32; ++it) {
        int idx = it * 256 + t;
        int d = idx & 127, ll = idx >> 7;
        tile[d][ll] = h[(size_t)(lb * 64 + ll) * HCOLS + 2 * D_ + nh * HD_ + d];
    }
    __syncthreads();
#pragma unroll
    for (int it = 0; it < 32; ++it) {
        int idx = it * 256 + t;
        int ll = idx & 63, d = idx >> 6;
        VT[((size_t)nh * HD_ + d) * L_ + lb * 64 + ll] = tile[d][ll];
    }
}

// ---------- gelu(tanh) on mlp part -> scratch cols D..D+MLP ----------
__global__ __launch_bounds__(256) void gelu_k(const u16* __restrict__ h, u16* __restrict__ S)
{
    int l = blockIdx.y;
    int m = blockIdx.x * 256 + threadIdx.x;  // 0..MLP
    float v = bf2f(h[(size_t)l * HCOLS + 3 * D_ + m]);
    float c = 0.7978845608028654f * (v + 0.044715f * v * v * v);
    float g = 0.5f * v * (1.f + tanhf(c));
    S[(size_t)l * SCOLS + D_ + m] = f2bf(g);
}

// ---------- softmax fp32 -> bf16 probs ----------
__global__ __launch_bounds__(256) void softmax_k(const float* __restrict__ S, u16* __restrict__ P)
{
    const int t = threadIdx.x;
    const float* sr = S + (size_t)blockIdx.x * L_;
    u16* pr = P + (size_t)blockIdx.x * L_;
    float v[8];
    float mx = -3.4e38f;
#pragma unroll
    for (int c = 0; c < 8; ++c) { v[c] = sr[c * 256 + t]; mx = fmaxf(mx, v[c]); }
    __shared__ float red[4];
    for (int off = 32; off; off >>= 1) mx = fmaxf(mx, __shfl_down(mx, off));
    if ((t & 63) == 0) red[t >> 6] = mx;
    __syncthreads();
    mx = fmaxf(fmaxf(red[0], red[1]), fmaxf(red[2], red[3]));
    float sum = 0.f;
#pragma unroll
    for (int c = 0; c < 8; ++c) { v[c] = __expf(v[c] - mx); sum += v[c]; }
    __syncthreads();
    for (int off = 32; off; off >>= 1) sum += __shfl_down(sum, off);
    if ((t & 63) == 0) red[t >> 6] = sum;
    __syncthreads();
    sum = red[0] + red[1] + red[2] + red[3];
    float inv = 1.f / sum;
#pragma unroll
    for (int c = 0; c < 8; ++c) pr[c * 256 + t] = f2bf(v[c] * inv);
}

// ---------- final: out = x + gate * g2 ----------
__global__ __launch_bounds__(256) void final_k(
    const float* __restrict__ x, const float* __restrict__ MOD,
    const float* __restrict__ G, float* __restrict__ out)
{
    int l = blockIdx.y;
    int d = blockIdx.x * 256 + threadIdx.x;
    size_t i = (size_t)l * D_ + d;
    out[i] = x[i] + MOD[2 * D_ + d] * G[i];
}

// ---------- ws layout (bytes) ----------
#define W1T_OFF   0ull                  // 21504x3072 bf16 = 132120576
#define XMOD_OFF  132120576ull          // 2048x3072 bf16  = 12582912
#define W2T_OFF   144703488ull          // 3072x15360 bf16 = 94371840
#define Q_OFF     239075328ull          // 24x2048x128 bf16 = 12582912
#define K_OFF     251658240ull
#define VT_OFF    264241152ull
#define SCR_OFF   276824064ull          // 2048x15360 bf16 = 62914560
#define MOD_OFF   339738624ull          // 9216 f32
#define SVEC_OFF  339775488ull          // 3072 f32
#define WS_NEED   339787776ull
// aliases (temporally dead regions):
#define SCORES_OFF 0ull                 // 4 heads fp32 = 67108864 (over dead W1T)
#define PROBS_OFF  67108864ull          // 4 heads bf16 = 33554432
#define G2_OFF     0ull                 // 2048x3072 f32 = 25165824 (after attention)

extern "C" void kernel_launch(void* const* d_in, const int* in_sizes, int n_in,
                              void* d_out, int out_size, void* d_ws, size_t ws_size,
                              hipStream_t stream)
{
    if (ws_size < WS_NEED) return;  // cannot run without scratch

    u16* hbuf = (u16*)d_in[0];  // scratchA input (unused by reference) holds h (bf16 2048x21504)
    const float* x     = (const float*)d_in[1];
    const float* vec   = (const float*)d_in[2];
    const float* pe    = (const float*)d_in[3];
    const float* mod_w = (const float*)d_in[4];
    const float* mod_b = (const float*)d_in[5];
    const float* w1    = (const float*)d_in[6];
    const float* b1    = (const float*)d_in[7];
    const float* w2    = (const float*)d_in[8];
    const float* b2    = (const float*)d_in[9];
    const float* qs    = (const float*)d_in[10];
    const float* ks    = (const float*)d_in[11];
    float* out = (float*)d_out;

    char* ws = (char*)d_ws;
    u16* W1T   = (u16*)(ws + W1T_OFF);
    u16* XMOD  = (u16*)(ws + XMOD_OFF);
    u16* W2T   = (u16*)(ws + W2T_OFF);
    u16* Qb    = (u16*)(ws + Q_OFF);
    u16* Kb    = (u16*)(ws + K_OFF);
    u16* VT    = (u16*)(ws + VT_OFF);
    u16* SCR   = (u16*)(ws + SCR_OFF);
    float* MOD  = (float*)(ws + MOD_OFF);
    float* SVEC = (float*)(ws + SVEC_OFF);
    float* SCORES = (float*)(ws + SCORES_OFF);
    u16* PROBS    = (u16*)(ws + PROBS_OFF);
    float* G2     = (float*)(ws + G2_OFF);

    // weight transposes -> bf16 (N,K)
    transpose_to_bf16<<<dim3(HCOLS / 32, D_ / 32), 256, 0, stream>>>(w1, W1T, D_, HCOLS);
    transpose_to_bf16<<<dim3(D_ / 32, SCOLS / 32), 256, 0, stream>>>(w2, W2T, SCOLS, D_);

    // modulation vector
    mod_init<<<36, 256, 0, stream>>>(mod_b, vec, MOD, SVEC);
    mod_gemv<<<dim3(36, 24), 256, 0, stream>>>(SVEC, mod_w, MOD);

    // layernorm + modulation
    ln_mod_k<<<L_, 256, 0, stream>>>(x, MOD, XMOD);

    // GEMM1: h = x_mod @ w1 + b1 (bf16 out into scratchA)
    gemm_bt<128, 128><<<dim3(HCOLS / 128, L_ / 128, 1), 256, 0, stream>>>(
        XMOD, W1T, b1, hbuf, L_, HCOLS, D_, HCOLS, 0, 0, 0, 1.f, 1);

    // qkv post-process
    qkv_rope<<<dim3(L_, NH_, 2), 128, 0, stream>>>(hbuf, pe, qs, ks, Qb, Kb);
    v_trans<<<dim3(L_ / 64, NH_), 256, 0, stream>>>(hbuf, VT);
    gelu_k<<<dim3(MLP_ / 256, L_), 256, 0, stream>>>(hbuf, SCR);

    // attention: 6 groups of 4 heads (scores fp32 + probs bf16 alias dead W1T/XMOD zone)
    const float ascale = 0.08838834764831845f;  // HD^-0.5
    for (int g = 0; g < 6; ++g) {
        const long long hoff = (long long)g * 4 * L_ * HD_;
        gemm_bt<128, 128><<<dim3(L_ / 128, L_ / 128, 4), 256, 0, stream>>>(
            Qb + hoff, Kb + hoff, nullptr, SCORES,
            L_, L_, HD_, L_, (long long)L_ * HD_, (long long)L_ * HD_, (long long)L_ * L_,
            ascale, 0);
        softmax_k<<<4 * L_, 256, 0, stream>>>(SCORES, PROBS);
        gemm_bt<64, 64><<<dim3(HD_ / 64, L_ / 64, 4), 256, 0, stream>>>(
            PROBS, VT + hoff, nullptr, SCR + (size_t)g * 4 * HD_,
            L_, HD_, L_, SCOLS, (long long)L_ * L_, (long long)HD_ * L_, HD_,
            1.f, 1);
    }

    // GEMM2: g2 = scratch @ w2 + b2 (fp32 out, aliases dead scores zone)
    gemm_bt<128, 128><<<dim3(D_ / 128, L_ / 128, 1), 256, 0, stream>>>(
        SCR, W2T, b2, G2, L_, D_, SCOLS, D_, 0, 0, 0, 1.f, 0);

    // residual + gate
    final_k<<<dim3(D_ / 256, L_), 256, 0, stream>>>(x, MOD, G2, out);
}

// Round 2
// 1718.668 us; speedup vs baseline: 1.1656x; 1.1656x over previous
//
#include <hip/hip_runtime.h>

typedef unsigned short u16;
typedef __bf16 bf16x8 __attribute__((ext_vector_type(8)));
typedef float f32x4 __attribute__((ext_vector_type(4)));

#define L_    2048
#define D_    3072
#define NH_   24
#define HD_   128
#define MLP_  12288
#define HCOLS 21504   // 3*D + MLP
#define QKVW  9216    // 3*D
#define SCOLS 15360   // D + MLP

// ---------- helpers ----------
__device__ __forceinline__ float bf2f(u16 u) { return __uint_as_float(((unsigned)u) << 16); }
__device__ __forceinline__ u16 f2bf(float f) {
    unsigned b = __float_as_uint(f);
    b += 0x7FFF + ((b >> 16) & 1);   // RNE
    return (u16)(b >> 16);
}
__device__ __forceinline__ void gld_lds16(const u16* g, u16* l) {
    __builtin_amdgcn_global_load_lds((const __attribute__((address_space(1))) void*)g,
                                     (__attribute__((address_space(3))) void*)l, 16, 0, 0);
}

// ---------- 128x128-tile GEMM: C = alpha * A(MxK) @ Bt(NxK)^T [+bias][epilogue] ----------
// blockIdx.x = M-tile (fastest -> consecutive blocks share the B col-tile for L2/LLC reuse)
// LDS layout XOR-swizzled: 16B chunk c of row r stored at chunk c^((r>>1)&3)
//   -> ds_read_b128 spreads over all 8 bank-groups (2-way only, free per m136)
// EPI: 1 = bf16 out, 2 = bf16 gelu(tanh) out, 3 = f32 resid + gate*(acc+bias)
template <int K, int LDC, int EPI>
__global__ __launch_bounds__(256) void gemm128(
    const u16* __restrict__ A, const u16* __restrict__ Bt,
    const float* __restrict__ bias, void* __restrict__ Cv,
    long long sA, long long sB, long long sC, float alpha,
    const float* __restrict__ resid, const float* __restrict__ gate)
{
    constexpr int BK = 32;
    __shared__ __align__(16) u16 As[128 * BK];
    __shared__ __align__(16) u16 Bs[128 * BK];
    const int t = threadIdx.x, w = t >> 6, lane = t & 63;
    const int quad = lane >> 4, r16 = lane & 15;
    const int m0 = blockIdx.x * 128;   // x fastest
    const int n0 = blockIdx.y * 128;
    const u16* Ab = A + (size_t)blockIdx.z * sA;
    const u16* Bb = Bt + (size_t)blockIdx.z * sB;
    const int wm = (w >> 1) * 64, wn = (w & 1) * 64;

    f32x4 acc[4][4];
#pragma unroll
    for (int i = 0; i < 4; ++i)
#pragma unroll
        for (int j = 0; j < 4; ++j) acc[i][j] = (f32x4){0.f, 0.f, 0.f, 0.f};

    for (int k0 = 0; k0 < K; k0 += BK) {
#pragma unroll
        for (int r = 0; r < 2; ++r) {
            int o = r * 4096 + w * 1024 + lane * 16;  // LDS byte offset
            int row = o >> 6, c = (o >> 4) & 3;
            int gc = c ^ ((row >> 1) & 3);            // swizzled source chunk
            gld_lds16(Ab + (size_t)(m0 + row) * K + k0 + gc * 8, As + (o >> 1));
        }
#pragma unroll
        for (int r = 0; r < 2; ++r) {
            int o = r * 4096 + w * 1024 + lane * 16;
            int row = o >> 6, c = (o >> 4) & 3;
            int gc = c ^ ((row >> 1) & 3);
            gld_lds16(Bb + (size_t)(n0 + row) * K + k0 + gc * 8, Bs + (o >> 1));
        }
        __syncthreads();  // drains vmcnt for global_load_lds
        bf16x8 af[4], bfr[4];
#pragma unroll
        for (int i = 0; i < 4; ++i) {
            int rA = wm + i * 16 + r16;
            af[i] = *(const bf16x8*)&As[rA * 32 + ((quad ^ ((rA >> 1) & 3)) << 3)];
        }
#pragma unroll
        for (int j = 0; j < 4; ++j) {
            int rB = wn + j * 16 + r16;
            bfr[j] = *(const bf16x8*)&Bs[rB * 32 + ((quad ^ ((rB >> 1) & 3)) << 3)];
        }
#pragma unroll
        for (int i = 0; i < 4; ++i)
#pragma unroll
            for (int j = 0; j < 4; ++j)
                acc[i][j] = __builtin_amdgcn_mfma_f32_16x16x32_bf16(af[i], bfr[j], acc[i][j], 0, 0, 0);
        __syncthreads();
    }

    // epilogue: C/D layout col = lane&15, row = quad*4 + reg  [m89/m91]
    if (EPI == 3) {
        float* Cb = (float*)Cv + (size_t)blockIdx.z * sC;
#pragma unroll
        for (int i = 0; i < 4; ++i)
#pragma unroll
            for (int rr = 0; rr < 4; ++rr) {
                int m = m0 + wm + i * 16 + quad * 4 + rr;
                float* crow = Cb + (size_t)m * LDC;
                const float* rrow = resid + (size_t)m * LDC;
#pragma unroll
                for (int j = 0; j < 4; ++j) {
                    int n = n0 + wn + j * 16 + r16;
                    float v = acc[i][j][rr] * alpha;
                    if (bias) v += bias[n];
                    crow[n] = rrow[n] + gate[n] * v;
                }
            }
    } else {
        u16* Cb = (u16*)Cv + (size_t)blockIdx.z * sC;
#pragma unroll
        for (int i = 0; i < 4; ++i)
#pragma unroll
            for (int rr = 0; rr < 4; ++rr) {
                int m = m0 + wm + i * 16 + quad * 4 + rr;
                u16* crow = Cb + (size_t)m * LDC;
#pragma unroll
                for (int j = 0; j < 4; ++j) {
                    int n = n0 + wn + j * 16 + r16;
                    float v = acc[i][j][rr] * alpha;
                    if (bias) v += bias[n];
                    if (EPI == 2) {  // gelu(tanh): v * sigmoid(2c)
                        float c = 0.7978845608028654f * (v + 0.044715f * v * v * v);
                        v = v / (1.f + __expf(-2.f * c));
                    }
                    crow[n] = f2bf(v);
                }
            }
    }
}

// ---------- transpose fp32 (R,C) -> bf16 (C,R) ----------
__global__ __launch_bounds__(256) void transpose_to_bf16(
    const float* __restrict__ in, u16* __restrict__ out, int R, int C)
{
    __shared__ float tile[32][33];
    int c0 = blockIdx.x * 32, r0 = blockIdx.y * 32;
    int tx = threadIdx.x & 31, ty = threadIdx.x >> 5;
#pragma unroll
    for (int i = 0; i < 32; i += 8)
        tile[ty + i][tx] = in[(size_t)(r0 + ty + i) * C + c0 + tx];
    __syncthreads();
#pragma unroll
    for (int i = 0; i < 32; i += 8)
        out[(size_t)(c0 + ty + i) * R + r0 + tx] = f2bf(tile[tx][ty + i]);
}

// ---------- mod: init + silu precompute ----------
__global__ void mod_init(const float* __restrict__ mod_b, const float* __restrict__ vec,
                         float* __restrict__ MOD, float* __restrict__ SVEC)
{
    int i = blockIdx.x * 256 + threadIdx.x;
    if (i < 3 * D_) MOD[i] = mod_b[i];
    if (i < D_) { float v = vec[i]; SVEC[i] = v / (1.f + __expf(-v)); }
}

// ---------- mod GEMV partial (atomic) ----------
__global__ __launch_bounds__(256) void mod_gemv(
    const float* __restrict__ SVEC, const float* __restrict__ mod_w, float* __restrict__ MOD)
{
    int n = blockIdx.x * 256 + threadIdx.x;
    int k0 = blockIdx.y * 128;
    float acc = 0.f;
#pragma unroll 8
    for (int kk = 0; kk < 128; ++kk)
        acc += SVEC[k0 + kk] * mod_w[(size_t)(k0 + kk) * (3 * D_) + n];
    atomicAdd(&MOD[n], acc);
}

// ---------- layernorm + modulation -> x_mod (bf16) ----------
__global__ __launch_bounds__(256) void ln_mod_k(
    const float* __restrict__ x, const float* __restrict__ MOD, u16* __restrict__ XMOD)
{
    int l = blockIdx.x, t = threadIdx.x;
    const float4* xr = (const float4*)(x + (size_t)l * D_);
    float4 v[3];
    float s = 0.f, ss = 0.f;
#pragma unroll
    for (int c = 0; c < 3; ++c) {
        v[c] = xr[c * 256 + t];
        s += v[c].x + v[c].y + v[c].z + v[c].w;
        ss += v[c].x * v[c].x + v[c].y * v[c].y + v[c].z * v[c].z + v[c].w * v[c].w;
    }
    __shared__ float rs[4], rss[4];
    float a = s, b = ss;
    for (int off = 32; off; off >>= 1) { a += __shfl_down(a, off); b += __shfl_down(b, off); }
    if ((t & 63) == 0) { rs[t >> 6] = a; rss[t >> 6] = b; }
    __syncthreads();
    float S = rs[0] + rs[1] + rs[2] + rs[3];
    float SS = rss[0] + rss[1] + rss[2] + rss[3];
    float mu = S * (1.f / D_);
    float var = SS * (1.f / D_) - mu * mu;
    float rstd = rsqrtf(var + 1e-6f);
    u16* orow = XMOD + (size_t)l * D_;
#pragma unroll
    for (int c = 0; c < 3; ++c) {
        int d0 = (c * 256 + t) * 4;
        float vals[4] = {v[c].x, v[c].y, v[c].z, v[c].w};
#pragma unroll
        for (int q = 0; q < 4; ++q) {
            int d = d0 + q;
            float o = MOD[d] + (1.f + MOD[D_ + d]) * ((vals[q] - mu) * rstd);
            orow[d] = f2bf(o);
        }
    }
}

// ---------- q/k: RMS norm + scale + rope -> (NH, L, HD) bf16 ----------
__global__ __launch_bounds__(128) void qkv_rope(
    const u16* __restrict__ h, const float* __restrict__ pe,
    const float* __restrict__ qs, const float* __restrict__ ks,
    u16* __restrict__ Q, u16* __restrict__ Kb)
{
    int l = blockIdx.x, nh = blockIdx.y, tt = blockIdx.z;  // tt: 0=q 1=k
    int d = threadIdx.x;                                   // 128 threads
    float xv = bf2f(h[(size_t)l * QKVW + tt * D_ + nh * HD_ + d]);
    __shared__ float red[2];
    __shared__ float ybuf[HD_];
    float sq = xv * xv;
    for (int off = 32; off; off >>= 1) sq += __shfl_down(sq, off);
    if ((d & 63) == 0) red[d >> 6] = sq;
    __syncthreads();
    float tot = red[0] + red[1];
    float rms = rsqrtf(tot * (1.f / HD_) + 1e-6f);
    const float* scale = (tt == 0) ? qs : ks;
    float y = xv * rms * scale[d];
    ybuf[d] = y;
    __syncthreads();
    int p = d >> 1, j = d & 1;
    float e = ybuf[2 * p], o = ybuf[2 * p + 1];
    const float* pb = pe + ((size_t)l * (HD_ / 2) + p) * 4 + j * 2;
    float out = pb[0] * e + pb[1] * o;
    u16* dst = (tt == 0) ? Q : Kb;
    dst[((size_t)nh * L_ + l) * HD_ + d] = f2bf(out);
}

// ---------- v transpose -> (NH, HD, L) bf16 ----------
__global__ __launch_bounds__(256) void v_trans(const u16* __restrict__ h, u16* __restrict__ VT)
{
    int lb = blockIdx.x, nh = blockIdx.y;
    __shared__ u16 tile[HD_][65];
    int t = threadIdx.x;
#pragma unroll
    for (int it = 0; it < 32; ++it) {
        int idx = it * 256 + t;
        int d = idx & 127, ll = idx >> 7;
        tile[d][ll] = h[(size_t)(lb * 64 + ll) * QKVW + 2 * D_ + nh * HD_ + d];
    }
    __syncthreads();
#pragma unroll
    for (int it = 0; it < 32; ++it) {
        int idx = it * 256 + t;
        int ll = idx & 63, d = idx >> 6;
        VT[((size_t)nh * HD_ + d) * L_ + lb * 64 + ll] = tile[d][ll];
    }
}

// ---------- softmax on bf16 scores, in-place (one block per 2048-row) ----------
__global__ __launch_bounds__(256) void softmax_bf(u16* __restrict__ S)
{
    const int t = threadIdx.x;
    uint4* row = (uint4*)(S + (size_t)blockIdx.x * L_);
    uint4 pk = row[t];  // 8 bf16
    unsigned u[4] = {pk.x, pk.y, pk.z, pk.w};
    float v[8];
#pragma unroll
    for (int c = 0; c < 4; ++c) {
        v[2 * c]     = bf2f((u16)(u[c] & 0xffff));
        v[2 * c + 1] = bf2f((u16)(u[c] >> 16));
    }
    float mx = -3.4e38f;
#pragma unroll
    for (int c = 0; c < 8; ++c) mx = fmaxf(mx, v[c]);
    __shared__ float red[4];
    for (int off = 32; off; off >>= 1) mx = fmaxf(mx, __shfl_down(mx, off));
    if ((t & 63) == 0) red[t >> 6] = mx;
    __syncthreads();
    mx = fmaxf(fmaxf(red[0], red[1]), fmaxf(red[2], red[3]));
    float s = 0.f;
#pragma unroll
    for (int c = 0; c < 8; ++c) { v[c] = __expf(v[c] - mx); s += v[c]; }
    __syncthreads();
    for (int off = 32; off; off >>= 1) s += __shfl_down(s, off);
    if ((t & 63) == 0) red[t >> 6] = s;
    __syncthreads();
    s = red[0] + red[1] + red[2] + red[3];
    float inv = 1.f / s;
#pragma unroll
    for (int c = 0; c < 4; ++c) {
        unsigned lo = f2bf(v[2 * c] * inv);
        unsigned hi = f2bf(v[2 * c + 1] * inv);
        u[c] = lo | (hi << 16);
    }
    row[t] = make_uint4(u[0], u[1], u[2], u[3]);
}

// ---------- ws layout (bytes) — total identical to round 1 (proven to fit) ----------
#define W1T_OFF   0ull                  // 21504x3072 bf16 = 132120576
#define XMOD_OFF  132120576ull          // 2048x3072 bf16  = 12582912
#define W2T_OFF   144703488ull          // 3072x15360 bf16 = 94371840
#define Q_OFF     239075328ull          // 24x2048x128 bf16 = 12582912
#define K_OFF     251658240ull
#define VT_OFF    264241152ull
#define SCR_OFF   276824064ull          // 2048x15360 bf16 = 62914560
#define MOD_OFF   339738624ull          // 9216 f32
#define SVEC_OFF  339775488ull          // 3072 f32
#define WS_NEED   339787776ull
// alias: bf16 scores/probs for 12 heads = 100663296 B over dead W1T+XMOD region
#define PROBS_OFF 0ull

extern "C" void kernel_launch(void* const* d_in, const int* in_sizes, int n_in,
                              void* d_out, int out_size, void* d_ws, size_t ws_size,
                              hipStream_t stream)
{
    if (ws_size < WS_NEED) return;

    u16* hbuf = (u16*)d_in[0];  // scratchA input buffer holds qkv (bf16 2048x9216)
    const float* x     = (const float*)d_in[1];
    const float* vec   = (const float*)d_in[2];
    const float* pe    = (const float*)d_in[3];
    const float* mod_w = (const float*)d_in[4];
    const float* mod_b = (const float*)d_in[5];
    const float* w1    = (const float*)d_in[6];
    const float* b1    = (const float*)d_in[7];
    const float* w2    = (const float*)d_in[8];
    const float* b2    = (const float*)d_in[9];
    const float* qs    = (const float*)d_in[10];
    const float* ks    = (const float*)d_in[11];
    float* out = (float*)d_out;

    char* ws = (char*)d_ws;
    u16* W1T   = (u16*)(ws + W1T_OFF);
    u16* XMOD  = (u16*)(ws + XMOD_OFF);
    u16* W2T   = (u16*)(ws + W2T_OFF);
    u16* Qb    = (u16*)(ws + Q_OFF);
    u16* Kb    = (u16*)(ws + K_OFF);
    u16* VT    = (u16*)(ws + VT_OFF);
    u16* SCR   = (u16*)(ws + SCR_OFF);
    float* MOD  = (float*)(ws + MOD_OFF);
    float* SVEC = (float*)(ws + SVEC_OFF);
    u16* PROBS  = (u16*)(ws + PROBS_OFF);

    // weight transposes -> bf16 (N,K)
    transpose_to_bf16<<<dim3(HCOLS / 32, D_ / 32), 256, 0, stream>>>(w1, W1T, D_, HCOLS);
    transpose_to_bf16<<<dim3(D_ / 32, SCOLS / 32), 256, 0, stream>>>(w2, W2T, SCOLS, D_);

    // modulation vector
    mod_init<<<36, 256, 0, stream>>>(mod_b, vec, MOD, SVEC);
    mod_gemv<<<dim3(36, 24), 256, 0, stream>>>(SVEC, mod_w, MOD);

    // layernorm + modulation
    ln_mod_k<<<L_, 256, 0, stream>>>(x, MOD, XMOD);

    // GEMM1a: qkv = x_mod @ w1[:, :9216] + b1  -> hbuf (bf16, ld 9216)
    gemm128<3072, QKVW, 1><<<dim3(16, QKVW / 128, 1), 256, 0, stream>>>(
        XMOD, W1T, b1, hbuf, 0, 0, 0, 1.f, nullptr, nullptr);
    // GEMM1b: mlp  = gelu(x_mod @ w1[:, 9216:] + b1[9216:]) -> SCR cols D..
    gemm128<3072, SCOLS, 2><<<dim3(16, MLP_ / 128, 1), 256, 0, stream>>>(
        XMOD, W1T + (size_t)QKVW * 3072, b1 + QKVW, SCR + D_, 0, 0, 0, 1.f, nullptr, nullptr);

    // qkv post-process
    qkv_rope<<<dim3(L_, NH_, 2), 128, 0, stream>>>(hbuf, pe, qs, ks, Qb, Kb);
    v_trans<<<dim3(L_ / 64, NH_), 256, 0, stream>>>(hbuf, VT);

    // attention: 2 groups of 12 heads, bf16 scores in dead W1T zone
    const float ascale = 0.08838834764831845f;  // HD^-0.5
    for (int g = 0; g < 2; ++g) {
        const long long hoff = (long long)g * 12 * L_ * HD_;
        gemm128<128, 2048, 1><<<dim3(16, 16, 12), 256, 0, stream>>>(
            Qb + hoff, Kb + hoff, nullptr, PROBS,
            (long long)L_ * HD_, (long long)L_ * HD_, (long long)L_ * L_,
            ascale, nullptr, nullptr);
        softmax_bf<<<12 * L_, 256, 0, stream>>>(PROBS);
        gemm128<2048, SCOLS, 1><<<dim3(16, 1, 12), 256, 0, stream>>>(
            PROBS, VT + hoff, nullptr, SCR + (size_t)g * 12 * HD_,
            (long long)L_ * L_, (long long)HD_ * L_, (long long)HD_,
            1.f, nullptr, nullptr);
    }

    // GEMM2 fused with residual: out = x + gate * (scratch @ w2 + b2)
    gemm128<15360, D_, 3><<<dim3(16, D_ / 128, 1), 256, 0, stream>>>(
        SCR, W2T, b2, out, 0, 0, 0, 1.f, x, MOD + 2 * D_);
}